// Round 4
// baseline (899.581 us; speedup 1.0000x reference)
//
#include <hip/hip_runtime.h>

typedef unsigned short u16;
typedef __attribute__((ext_vector_type(8))) short short8;
typedef __attribute__((ext_vector_type(4))) float floatx4;

#define NN 50000
#define NE 1600000
#define BN_EPS 1e-5f

__device__ __forceinline__ float bfu(u16 u) {
    union { unsigned u32; float f; } v; v.u32 = ((unsigned)u) << 16; return v.f;
}
__device__ __forceinline__ u16 f2bf(float f) {
    union { float f; unsigned u; } v; v.f = f;
    unsigned r = v.u + 0x7FFFu + ((v.u >> 16) & 1u);
    return (u16)(r >> 16);
}
// mode m: 1 = buffers hold float32, 0 = buffers hold bf16
__device__ __forceinline__ float ldf(const void* p, int i, int m) {
    return m ? ((const float*)p)[i] : bfu(((const u16*)p)[i]);
}

// K0: dtype detection (f32 reinterpreted as bf16 -> random-exponent garbage).
__global__ __launch_bounds__(256) void k_detect(const u16* __restrict__ x, int* __restrict__ mode) {
    float mx = 0.f;
    for (int i = threadIdx.x; i < 4096; i += 256) mx = fmaxf(mx, fabsf(bfu(x[i])));
#pragma unroll
    for (int o = 32; o > 0; o >>= 1) mx = fmaxf(mx, __shfl_down(mx, o));
    __shared__ float s[4];
    if ((threadIdx.x & 63) == 0) s[threadIdx.x >> 6] = mx;
    __syncthreads();
    if (threadIdx.x == 0) {
        float m2 = fmaxf(fmaxf(s[0], s[1]), fmaxf(s[2], s[3]));
        mode[0] = (m2 > 1e4f) ? 1 : 0;
    }
}

// K0b: canonicalize MFMA-consumed weights to bf16 ws copies.
// dst: Wfe0[16384] | We1[8192] | Wfn0[16384] | Wn1[8192] | Wfn1[16384]
__global__ __launch_bounds__(256) void k_cvtw(const void* __restrict__ W0, const void* __restrict__ W1,
                                              const void* __restrict__ W2, const void* __restrict__ W3,
                                              const void* __restrict__ W4,
                                              u16* __restrict__ dst, const int* __restrict__ mf) {
    int m = mf[0];
    int i = blockIdx.x * 256 + threadIdx.x;   // 65536 total
    const void* src; int off;
    if (i < 16384)      { src = W0; off = i; }
    else if (i < 24576) { src = W1; off = i - 16384; }
    else if (i < 40960) { src = W2; off = i - 24576; }
    else if (i < 49152) { src = W3; off = i - 40960; }
    else                { src = W4; off = i - 49152; }
    dst[i] = m ? f2bf(((const float*)src)[off]) : ((const u16*)src)[off];
}

// K1: n1_l0[n][c] = relu(sum_i x[n][i]*Wn0[c][i])  [50000 x 64] bf16.
__global__ __launch_bounds__(256) void k_enc0(const void* __restrict__ x, const void* __restrict__ Wn,
                                              u16* __restrict__ n1, const int* __restrict__ mf) {
    int m = mf[0];
    __shared__ float Wns[64 * 17];
    __shared__ float xsh[4][16];
    int t = threadIdx.x;
    int n0 = blockIdx.x * 4;
    for (int i = t; i < 1024; i += 256) Wns[(i >> 4) * 17 + (i & 15)] = ldf(Wn, i, m);
    if (t < 64) xsh[t >> 4][t & 15] = ldf(x, n0 * 16 + t, m);
    __syncthreads();
    int n = t >> 6, c = t & 63;
    float acc = 0.f;
#pragma unroll
    for (int i = 0; i < 16; i++) acc += xsh[n][i] * Wns[c * 17 + i];
    n1[(n0 + n) * 64 + c] = f2bf(fmaxf(acc, 0.f));
}

// K_PN: P[j] = sum_k relu(We0[k])*Wfe0[j][64+k]; N[j] = sum_k min(We0[k],0)*Wfe0[j][64+k]
__global__ void k_pn(const void* __restrict__ We0, const void* __restrict__ Wfe0,
                     float* __restrict__ PN, const int* __restrict__ mf) {
    int m = mf[0];
    int j = threadIdx.x;  // 128
    float p = 0.f, n = 0.f;
    for (int k = 0; k < 64; k++) {
        float w = ldf(We0, k, m);
        float wf = ldf(Wfe0, j * 128 + 64 + k, m);
        p += fmaxf(w, 0.f) * wf;
        n += fminf(w, 0.f) * wf;
    }
    PN[j] = p; PN[128 + j] = n;
}

// SORT pass 1: histogram of dst
__global__ __launch_bounds__(256) void k_hist(const int* __restrict__ ei, int* __restrict__ off) {
    int e = blockIdx.x * 256 + threadIdx.x;
    atomicAdd(off + ei[NE + e], 1);
}

// SORT pass 2: exclusive scan of off[50000] in-place (single block, 1024 threads)
__global__ __launch_bounds__(1024) void k_scan(int* __restrict__ off) {
    __shared__ int part[1024];
    int t = threadIdx.x;
    int base = t * 49;
    int lim = 50000 - base; if (lim > 49) lim = 49; if (lim < 0) lim = 0;
    int s = 0;
    for (int i = 0; i < lim; i++) s += off[base + i];
    part[t] = s;
    __syncthreads();
    for (int o = 1; o < 1024; o <<= 1) {
        int v = (t >= o) ? part[t - o] : 0;
        __syncthreads();
        part[t] += v;
        __syncthreads();
    }
    int run = (t > 0) ? part[t - 1] : 0;
    for (int i = 0; i < lim; i++) { int v = off[base + i]; off[base + i] = run; run += v; }
}

// SORT pass 3: scatter edges into dst-sorted order. sd = src | dst<<16, ae bf16.
__global__ __launch_bounds__(256) void k_scatter(const int* __restrict__ ei, const void* __restrict__ ea,
                                                 int* __restrict__ off,
                                                 unsigned* __restrict__ ssd, u16* __restrict__ sae,
                                                 const int* __restrict__ mf) {
    int m = mf[0];
    int e = blockIdx.x * 256 + threadIdx.x;
    int srcv = ei[e], d = ei[NE + e];
    int p = atomicAdd(off + d, 1);
    ssd[p] = (unsigned)srcv | ((unsigned)d << 16);
    sae[p] = f2bf(ldf(ea, e, m));
}

// K5: fused edge pipeline over dst-sorted edges, MFMA + segmented reduction.
// Also produces sp/sn (per-dst +/- ae sums) as a side product.
__global__ __launch_bounds__(256) void k_edge(
    const unsigned* __restrict__ ssd, const u16* __restrict__ sae,
    const u16* __restrict__ n1l0,
    const u16* __restrict__ Wfe0c, const void* __restrict__ bfe0,
    const float* __restrict__ PN,
    const u16* __restrict__ We1c,
    float* __restrict__ agg, float* __restrict__ sp, float* __restrict__ sn,
    const int* __restrict__ mf) {
    int m = mf[0];
    __shared__ __align__(16) u16 h0s[64][72];
    __shared__ __align__(16) u16 h1s[64][136];
    __shared__ __align__(16) float h2s[64][68];
    __shared__ float aes[64];
    __shared__ unsigned sd[64];
    int t = threadIdx.x;
    int e0 = blockIdx.x * 64;
    if (t < 64) {
        sd[t] = ssd[e0 + t];
        aes[t] = bfu(sae[e0 + t]);
    }
    __syncthreads();
    // stage h0 = n1l0[src] + n1l0[dst] (64 edges x 64 ch); dst nearly constant -> L1-hot
#pragma unroll
    for (int i = 0; i < 16; i++) {
        int idx = i * 256 + t;
        int e = idx >> 6, c = idx & 63;
        unsigned p = sd[e];
        int s = p & 0xFFFF, d = p >> 16;
        float v = bfu(n1l0[s * 64 + c]) + bfu(n1l0[d * 64 + c]);
        h0s[e][c] = f2bf(v);
    }
    __syncthreads();
    int lane = t & 63, w = t >> 6, q = lane >> 4, nidx = lane & 15;
    // GEMM1: h1 = relu(h0 @ Wfe0[:, :64]^T + ae*PN + bfe0); wave w: edge rows w*16..+16
    {
        const u16* ar = &h0s[w * 16 + nidx][0];
        short8 a0 = *(const short8*)&ar[q * 8];
        short8 a1 = *(const short8*)&ar[32 + q * 8];
#pragma unroll
        for (int jt = 0; jt < 8; jt++) {
            int j = jt * 16 + nidx;
            const u16* wr = Wfe0c + j * 128;
            floatx4 acc = {0.f, 0.f, 0.f, 0.f};
            acc = __builtin_amdgcn_mfma_f32_16x16x32_bf16(a0, *(const short8*)&wr[q * 8], acc, 0, 0, 0);
            acc = __builtin_amdgcn_mfma_f32_16x16x32_bf16(a1, *(const short8*)&wr[32 + q * 8], acc, 0, 0, 0);
            float bias = ldf(bfe0, j, m);
            float Pj = PN[j], Nj = PN[128 + j];
#pragma unroll
            for (int r = 0; r < 4; r++) {
                int e = w * 16 + q * 4 + r;   // D: row=(lane>>4)*4+reg, col=lane&15
                float a = aes[e];
                float v = acc[r] + bias + a * (a > 0.f ? Pj : Nj);
                h1s[e][j] = f2bf(fmaxf(v, 0.f));
            }
        }
    }
    __syncthreads();
    // GEMM2: e1' = relu(h1 @ We1^T) -> h2s (f32)
    {
        const u16* ar = &h1s[w * 16 + nidx][0];
        short8 a0 = *(const short8*)&ar[q * 8];
        short8 a1 = *(const short8*)&ar[32 + q * 8];
        short8 a2 = *(const short8*)&ar[64 + q * 8];
        short8 a3 = *(const short8*)&ar[96 + q * 8];
#pragma unroll
        for (int ct = 0; ct < 4; ct++) {
            int c = ct * 16 + nidx;
            const u16* wr = We1c + c * 128;
            floatx4 acc = {0.f, 0.f, 0.f, 0.f};
            acc = __builtin_amdgcn_mfma_f32_16x16x32_bf16(a0, *(const short8*)&wr[q * 8], acc, 0, 0, 0);
            acc = __builtin_amdgcn_mfma_f32_16x16x32_bf16(a1, *(const short8*)&wr[32 + q * 8], acc, 0, 0, 0);
            acc = __builtin_amdgcn_mfma_f32_16x16x32_bf16(a2, *(const short8*)&wr[64 + q * 8], acc, 0, 0, 0);
            acc = __builtin_amdgcn_mfma_f32_16x16x32_bf16(a3, *(const short8*)&wr[96 + q * 8], acc, 0, 0, 0);
#pragma unroll
            for (int r = 0; r < 4; r++) {
                int e = w * 16 + q * 4 + r;
                h2s[e][c] = fmaxf(acc[r], 0.f);
            }
        }
    }
    __syncthreads();
    // segmented reduction over sorted dst runs: threads 0..127 -> (channel, half)
    if (t < 128) {
        int c = t & 63;
        int ebeg = (t >> 6) * 32, eend = ebeg + 32;
        float s = 0.f;
        int cur = sd[ebeg] >> 16;
        for (int e = ebeg; e < eend; e++) {
            int d = sd[e] >> 16;
            if (d != cur) { atomicAdd(agg + cur * 64 + c, s); s = 0.f; cur = d; }
            s += h2s[e][c];
        }
        atomicAdd(agg + cur * 64 + c, s);
    } else if (t < 130) {
        // side product: sp/sn per-dst +/- ae sums
        int ebeg = (t - 128) * 32, eend = ebeg + 32;
        float p = 0.f, n = 0.f;
        int cur = sd[ebeg] >> 16;
        for (int e = ebeg; e < eend; e++) {
            int d = sd[e] >> 16;
            if (d != cur) {
                if (p != 0.f) atomicAdd(sp + cur, p);
                if (n != 0.f) atomicAdd(sn + cur, n);
                p = 0.f; n = 0.f; cur = d;
            }
            float a = aes[e];
            p += fmaxf(a, 0.f); n += fminf(a, 0.f);
        }
        if (p != 0.f) atomicAdd(sp + cur, p);
        if (n != 0.f) atomicAdd(sn + cur, n);
    }
}

// K34: fused node MLP l0 + BN + node encoder l1 -> n1_l1 [50000 x 64] bf16. MFMA, 64 nodes/block.
__global__ __launch_bounds__(256) void k_node_l0(
    const u16* __restrict__ n1l0, const float* __restrict__ sp, const float* __restrict__ sn,
    const void* __restrict__ We0, const u16* __restrict__ Wfn0c, const void* __restrict__ bfn0,
    const void* __restrict__ g0, const void* __restrict__ b0,
    const void* __restrict__ rm0, const void* __restrict__ rv0,
    const u16* __restrict__ Wn1c, u16* __restrict__ n1l1, const int* __restrict__ mf) {
    int m = mf[0];
    __shared__ __align__(16) u16 fs[64][136];
    __shared__ __align__(16) u16 xs[64][136];
    int t = threadIdx.x;
    int n0 = blockIdx.x * 64;
    {
        int col = t & 127;
        int rbase = t >> 7;
        float wp = 0.f, wn = 0.f;
        if (col < 64) { float w0 = ldf(We0, col, m); wp = fmaxf(w0, 0.f); wn = fminf(w0, 0.f); }
#pragma unroll
        for (int i = 0; i < 32; i++) {
            int row = rbase + 2 * i;
            int n = n0 + row;
            float v = 0.f;
            if (n < NN) v = (col < 64) ? (wp * sp[n] + wn * sn[n]) : bfu(n1l0[n * 64 + col - 64]);
            fs[row][col] = f2bf(v);
        }
    }
    __syncthreads();
    int lane = t & 63, w = t >> 6, q = lane >> 4, nidx = lane & 15;
    {
        const u16* ar = &fs[w * 16 + nidx][0];
        short8 a0 = *(const short8*)&ar[q * 8];
        short8 a1 = *(const short8*)&ar[32 + q * 8];
        short8 a2 = *(const short8*)&ar[64 + q * 8];
        short8 a3 = *(const short8*)&ar[96 + q * 8];
#pragma unroll
        for (int jt = 0; jt < 8; jt++) {
            int j = jt * 16 + nidx;
            const u16* wr = Wfn0c + j * 128;
            floatx4 acc = {0.f, 0.f, 0.f, 0.f};
            acc = __builtin_amdgcn_mfma_f32_16x16x32_bf16(a0, *(const short8*)&wr[q * 8], acc, 0, 0, 0);
            acc = __builtin_amdgcn_mfma_f32_16x16x32_bf16(a1, *(const short8*)&wr[32 + q * 8], acc, 0, 0, 0);
            acc = __builtin_amdgcn_mfma_f32_16x16x32_bf16(a2, *(const short8*)&wr[64 + q * 8], acc, 0, 0, 0);
            acc = __builtin_amdgcn_mfma_f32_16x16x32_bf16(a3, *(const short8*)&wr[96 + q * 8], acc, 0, 0, 0);
            float bias = ldf(bfn0, j, m);
            float sc = ldf(g0, j, m) * rsqrtf(ldf(rv0, j, m) + BN_EPS);
            float sh = ldf(b0, j, m) - ldf(rm0, j, m) * sc;
#pragma unroll
            for (int r = 0; r < 4; r++) {
                int row = w * 16 + q * 4 + r;
                xs[row][j] = f2bf(fmaxf(acc[r] + bias, 0.f) * sc + sh);
            }
        }
    }
    __syncthreads();
    {
        const u16* ar = &xs[w * 16 + nidx][0];
        short8 a0 = *(const short8*)&ar[q * 8];
        short8 a1 = *(const short8*)&ar[32 + q * 8];
        short8 a2 = *(const short8*)&ar[64 + q * 8];
        short8 a3 = *(const short8*)&ar[96 + q * 8];
#pragma unroll
        for (int jt = 0; jt < 4; jt++) {
            int j = jt * 16 + nidx;
            const u16* wr = Wn1c + j * 128;
            floatx4 acc = {0.f, 0.f, 0.f, 0.f};
            acc = __builtin_amdgcn_mfma_f32_16x16x32_bf16(a0, *(const short8*)&wr[q * 8], acc, 0, 0, 0);
            acc = __builtin_amdgcn_mfma_f32_16x16x32_bf16(a1, *(const short8*)&wr[32 + q * 8], acc, 0, 0, 0);
            acc = __builtin_amdgcn_mfma_f32_16x16x32_bf16(a2, *(const short8*)&wr[64 + q * 8], acc, 0, 0, 0);
            acc = __builtin_amdgcn_mfma_f32_16x16x32_bf16(a3, *(const short8*)&wr[96 + q * 8], acc, 0, 0, 0);
#pragma unroll
            for (int r = 0; r < 4; r++) {
                int row = w * 16 + q * 4 + r;
                int n = n0 + row;
                if (n < NN) n1l1[n * 64 + j] = f2bf(fmaxf(acc[r], 0.f));
            }
        }
    }
}

// K6: node MLP l1 + BN -> d_out. MFMA, 64 nodes/block.
__global__ __launch_bounds__(256) void k_node_l1(
    const u16* __restrict__ n1l1, const float* __restrict__ agg,
    const u16* __restrict__ Wfn1c, const void* __restrict__ bfn1,
    const void* __restrict__ g1, const void* __restrict__ b1,
    const void* __restrict__ rm1, const void* __restrict__ rv1,
    void* __restrict__ out, const int* __restrict__ mf) {
    int m = mf[0];
    __shared__ __align__(16) u16 fs[64][136];
    int t = threadIdx.x;
    int n0 = blockIdx.x * 64;
    {
        int col = t & 127;
        int rbase = t >> 7;
#pragma unroll
        for (int i = 0; i < 32; i++) {
            int row = rbase + 2 * i;
            int n = n0 + row;
            float v = 0.f;
            if (n < NN) v = (col < 64) ? agg[n * 64 + col] : bfu(n1l1[n * 64 + col - 64]);
            fs[row][col] = f2bf(v);
        }
    }
    __syncthreads();
    int lane = t & 63, w = t >> 6, q = lane >> 4, nidx = lane & 15;
    const u16* ar = &fs[w * 16 + nidx][0];
    short8 a0 = *(const short8*)&ar[q * 8];
    short8 a1 = *(const short8*)&ar[32 + q * 8];
    short8 a2 = *(const short8*)&ar[64 + q * 8];
    short8 a3 = *(const short8*)&ar[96 + q * 8];
#pragma unroll
    for (int jt = 0; jt < 8; jt++) {
        int j = jt * 16 + nidx;
        const u16* wr = Wfn1c + j * 128;
        floatx4 acc = {0.f, 0.f, 0.f, 0.f};
        acc = __builtin_amdgcn_mfma_f32_16x16x32_bf16(a0, *(const short8*)&wr[q * 8], acc, 0, 0, 0);
        acc = __builtin_amdgcn_mfma_f32_16x16x32_bf16(a1, *(const short8*)&wr[32 + q * 8], acc, 0, 0, 0);
        acc = __builtin_amdgcn_mfma_f32_16x16x32_bf16(a2, *(const short8*)&wr[64 + q * 8], acc, 0, 0, 0);
        acc = __builtin_amdgcn_mfma_f32_16x16x32_bf16(a3, *(const short8*)&wr[96 + q * 8], acc, 0, 0, 0);
        float bias = ldf(bfn1, j, m);
        float sc = ldf(g1, j, m) * rsqrtf(ldf(rv1, j, m) + BN_EPS);
        float sh = ldf(b1, j, m) - ldf(rm1, j, m) * sc;
#pragma unroll
        for (int r = 0; r < 4; r++) {
            int row = w * 16 + q * 4 + r;
            int n = n0 + row;
            if (n < NN) {
                float v = fmaxf(acc[r] + bias, 0.f) * sc + sh;
                if (m) ((float*)out)[n * 128 + j] = v;
                else   ((u16*)out)[n * 128 + j] = f2bf(v);
            }
        }
    }
}

extern "C" void kernel_launch(void* const* d_in, const int* in_sizes, int n_in,
                              void* d_out, int out_size, void* d_ws, size_t ws_size,
                              hipStream_t stream) {
    const void* x    = d_in[0];
    const void* ea   = d_in[1];
    const int*  ei   = (const int*)d_in[2];
    const void* Wn0  = d_in[3];
    const void* We0  = d_in[4];
    const void* Wfn0 = d_in[5];
    const void* bfn0 = d_in[6];
    const void* Wfe0 = d_in[7];
    const void* bfe0 = d_in[8];
    const void* g0   = d_in[9];
    const void* b0   = d_in[10];
    const void* rm0  = d_in[11];
    const void* rv0  = d_in[12];
    const void* Wn1  = d_in[13];
    const void* We1  = d_in[14];
    const void* Wfn1 = d_in[15];
    const void* bfn1 = d_in[16];
    // d_in[17]/d_in[18] (l1_Wfe/l1_bfe): dead — layer-1 edge output discarded
    const void* g1   = d_in[19];
    const void* b1   = d_in[20];
    const void* rm1  = d_in[21];
    const void* rv1  = d_in[22];

    float* wsf = (float*)d_ws;
    float*    agg  = wsf;                         // 3.2M f32
    u16*      n1l0 = (u16*)(wsf + 3200000);       // 3.2M u16 (1.6M slots)
    unsigned* ssd  = (unsigned*)(wsf + 4800000);  // 1.6M uint — later aliased as n1l1
    u16*      n1l1 = (u16*)(wsf + 4800000);       // alias: written after ssd is dead
    u16*      sae  = (u16*)(wsf + 6400000);       // 1.6M u16 (0.8M slots)
    float*    sp   = wsf + 7200000;               // 50K
    float*    sn   = wsf + 7250000;               // 50K
    float*    PN   = wsf + 7300000;               // 256
    u16*      Wc   = (u16*)(wsf + 7300256);       // 65,536 u16 (32,768 slots)
    int*      off  = (int*)(wsf + 7333024);       // 50,000 int
    int*      mode = (int*)(wsf + 7383024);
    u16* Wfe0c = Wc;
    u16* We1c  = Wc + 16384;
    u16* Wfn0c = Wc + 24576;
    u16* Wn1c  = Wc + 40960;
    u16* Wfn1c = Wc + 49152;

    hipMemsetAsync(sp, 0, 100000 * sizeof(float), stream);   // sp + sn
    hipMemsetAsync(agg, 0, 3200000 * sizeof(float), stream);
    hipMemsetAsync(off, 0, 50000 * sizeof(int), stream);

    k_detect<<<1, 256, 0, stream>>>((const u16*)x, mode);
    k_cvtw<<<256, 256, 0, stream>>>(Wfe0, We1, Wfn0, Wn1, Wfn1, Wc, mode);
    k_enc0<<<12500, 256, 0, stream>>>(x, Wn0, n1l0, mode);
    k_pn<<<1, 128, 0, stream>>>(We0, Wfe0, PN, mode);
    k_hist<<<6250, 256, 0, stream>>>(ei, off);
    k_scan<<<1, 1024, 0, stream>>>(off);
    k_scatter<<<6250, 256, 0, stream>>>(ei, ea, off, ssd, sae, mode);
    k_edge<<<25000, 256, 0, stream>>>(ssd, sae, n1l0, Wfe0c, bfe0, PN, We1c,
                                      agg, sp, sn, mode);
    k_node_l0<<<782, 256, 0, stream>>>(n1l0, sp, sn, We0, Wfn0c, bfn0,
                                       g0, b0, rm0, rv0, Wn1c, n1l1, mode);
    k_node_l1<<<782, 256, 0, stream>>>(n1l1, agg, Wfn1c, bfn1,
                                       g1, b1, rm1, rv1, d_out, mode);
}

// Round 5
// 803.204 us; speedup vs baseline: 1.1200x; 1.1200x over previous
//
#include <hip/hip_runtime.h>

typedef unsigned short u16;
typedef __attribute__((ext_vector_type(8))) short short8;
typedef __attribute__((ext_vector_type(4))) float floatx4;

#define NN 50000
#define NE 1600000
#define BN_EPS 1e-5f

__device__ __forceinline__ float bfu(u16 u) {
    union { unsigned u32; float f; } v; v.u32 = ((unsigned)u) << 16; return v.f;
}
__device__ __forceinline__ u16 f2bf(float f) {
    union { float f; unsigned u; } v; v.f = f;
    unsigned r = v.u + 0x7FFFu + ((v.u >> 16) & 1u);
    return (u16)(r >> 16);
}
// mode m: 1 = buffers hold float32, 0 = buffers hold bf16
__device__ __forceinline__ float ldf(const void* p, int i, int m) {
    return m ? ((const float*)p)[i] : bfu(((const u16*)p)[i]);
}

// K0: dtype detection (f32 reinterpreted as bf16 -> random-exponent garbage).
__global__ __launch_bounds__(256) void k_detect(const u16* __restrict__ x, int* __restrict__ mode) {
    float mx = 0.f;
    for (int i = threadIdx.x; i < 4096; i += 256) mx = fmaxf(mx, fabsf(bfu(x[i])));
#pragma unroll
    for (int o = 32; o > 0; o >>= 1) mx = fmaxf(mx, __shfl_down(mx, o));
    __shared__ float s[4];
    if ((threadIdx.x & 63) == 0) s[threadIdx.x >> 6] = mx;
    __syncthreads();
    if (threadIdx.x == 0) {
        float m2 = fmaxf(fmaxf(s[0], s[1]), fmaxf(s[2], s[3]));
        mode[0] = (m2 > 1e4f) ? 1 : 0;
    }
}

// K0b: canonicalize MFMA-consumed weights to bf16 ws copies.
// dst: Wfe0[16384] | We1[8192] | Wfn0[16384] | Wn1[8192] | Wfn1[16384]
__global__ __launch_bounds__(256) void k_cvtw(const void* __restrict__ W0, const void* __restrict__ W1,
                                              const void* __restrict__ W2, const void* __restrict__ W3,
                                              const void* __restrict__ W4,
                                              u16* __restrict__ dst, const int* __restrict__ mf) {
    int m = mf[0];
    int i = blockIdx.x * 256 + threadIdx.x;   // 65536 total
    const void* src; int off;
    if (i < 16384)      { src = W0; off = i; }
    else if (i < 24576) { src = W1; off = i - 16384; }
    else if (i < 40960) { src = W2; off = i - 24576; }
    else if (i < 49152) { src = W3; off = i - 40960; }
    else                { src = W4; off = i - 49152; }
    dst[i] = m ? f2bf(((const float*)src)[off]) : ((const u16*)src)[off];
}

// K1: n1_l0[n][c] = relu(sum_i x[n][i]*Wn0[c][i])  [50000 x 64] bf16.
__global__ __launch_bounds__(256) void k_enc0(const void* __restrict__ x, const void* __restrict__ Wn,
                                              u16* __restrict__ n1, const int* __restrict__ mf) {
    int m = mf[0];
    __shared__ float Wns[64 * 17];
    __shared__ float xsh[4][16];
    int t = threadIdx.x;
    int n0 = blockIdx.x * 4;
    for (int i = t; i < 1024; i += 256) Wns[(i >> 4) * 17 + (i & 15)] = ldf(Wn, i, m);
    if (t < 64) xsh[t >> 4][t & 15] = ldf(x, n0 * 16 + t, m);
    __syncthreads();
    int n = t >> 6, c = t & 63;
    float acc = 0.f;
#pragma unroll
    for (int i = 0; i < 16; i++) acc += xsh[n][i] * Wns[c * 17 + i];
    n1[(n0 + n) * 64 + c] = f2bf(fmaxf(acc, 0.f));
}

// K_PN: P[j] = sum_k relu(We0[k])*Wfe0[j][64+k]; N[j] = sum_k min(We0[k],0)*Wfe0[j][64+k]
__global__ void k_pn(const void* __restrict__ We0, const void* __restrict__ Wfe0,
                     float* __restrict__ PN, const int* __restrict__ mf) {
    int m = mf[0];
    int j = threadIdx.x;  // 128
    float p = 0.f, n = 0.f;
    for (int k = 0; k < 64; k++) {
        float w = ldf(We0, k, m);
        float wf = ldf(Wfe0, j * 128 + 64 + k, m);
        p += fmaxf(w, 0.f) * wf;
        n += fminf(w, 0.f) * wf;
    }
    PN[j] = p; PN[128 + j] = n;
}

// SORT pass 1: histogram of dst
__global__ __launch_bounds__(256) void k_hist(const int* __restrict__ ei, int* __restrict__ off) {
    int e = blockIdx.x * 256 + threadIdx.x;
    atomicAdd(off + ei[NE + e], 1);
}

// SORT scan (two-level, 196 blocks): pass A — per-block sums of 256-int chunks
__global__ __launch_bounds__(256) void k_scan1(const int* __restrict__ off, int* __restrict__ bs) {
    __shared__ int sh[4];
    int t = threadIdx.x;
    int i = blockIdx.x * 256 + t;
    int v = (i < NN) ? off[i] : 0;
#pragma unroll
    for (int o = 32; o > 0; o >>= 1) v += __shfl_down(v, o);
    if ((t & 63) == 0) sh[t >> 6] = v;
    __syncthreads();
    if (t == 0) bs[blockIdx.x] = sh[0] + sh[1] + sh[2] + sh[3];
}

// pass B — single tiny block: exclusive scan of 196 block sums
__global__ __launch_bounds__(256) void k_scan2(int* __restrict__ bs) {
    __shared__ int s[256];
    int t = threadIdx.x;
    int v = (t < 196) ? bs[t] : 0;
    s[t] = v;
    __syncthreads();
    for (int o = 1; o < 256; o <<= 1) {
        int u = (t >= o) ? s[t - o] : 0;
        __syncthreads();
        s[t] += u;
        __syncthreads();
    }
    if (t < 196) bs[t] = s[t] - v;   // exclusive
}

// pass C — per-chunk exclusive scan + block offset
__global__ __launch_bounds__(256) void k_scan3(int* __restrict__ off, const int* __restrict__ bs) {
    __shared__ int s[256];
    int t = threadIdx.x;
    int i = blockIdx.x * 256 + t;
    int v = (i < NN) ? off[i] : 0;
    s[t] = v;
    __syncthreads();
    for (int o = 1; o < 256; o <<= 1) {
        int u = (t >= o) ? s[t - o] : 0;
        __syncthreads();
        s[t] += u;
        __syncthreads();
    }
    if (i < NN) off[i] = bs[blockIdx.x] + s[t] - v;   // exclusive
}

// SORT pass 3: scatter edges into dst-sorted order. sd = src | dst<<16, ae bf16.
__global__ __launch_bounds__(256) void k_scatter(const int* __restrict__ ei, const void* __restrict__ ea,
                                                 int* __restrict__ off,
                                                 unsigned* __restrict__ ssd, u16* __restrict__ sae,
                                                 const int* __restrict__ mf) {
    int m = mf[0];
    int e = blockIdx.x * 256 + threadIdx.x;
    int srcv = ei[e], d = ei[NE + e];
    int p = atomicAdd(off + d, 1);
    ssd[p] = (unsigned)srcv | ((unsigned)d << 16);
    sae[p] = f2bf(ldf(ea, e, m));
}

// K5: fused edge pipeline over dst-sorted edges.
// GEMM1 A-frags built in registers straight from global (MFMA linearity:
// (n1[src]+n1[dst])@W = n1[src]@W + n1[dst]@W) — no staging LDS, no cvt.
__global__ __launch_bounds__(256) void k_edge(
    const unsigned* __restrict__ ssd, const u16* __restrict__ sae,
    const u16* __restrict__ n1l0,
    const u16* __restrict__ Wfe0c, const void* __restrict__ bfe0,
    const float* __restrict__ PN,
    const u16* __restrict__ We1c,
    float* __restrict__ agg, float* __restrict__ sp, float* __restrict__ sn,
    const int* __restrict__ mf) {
    int m = mf[0];
    __shared__ __align__(16) u16 h1s[64][136];   // 17408 B
    __shared__ __align__(16) u16 h2s[64][72];    //  9216 B (bf16 e1')
    __shared__ float aes[64];
    __shared__ unsigned sd[64];
    int t = threadIdx.x;
    int e0 = blockIdx.x * 64;
    if (t < 64) {
        sd[t] = ssd[e0 + t];
        aes[t] = bfu(sae[e0 + t]);
    }
    __syncthreads();
    int lane = t & 63, w = t >> 6, q = lane >> 4, nidx = lane & 15;
    // GEMM1: h1 = relu(h0 @ Wfe0[:, :64]^T + ae*PN + bfe0); wave w: edge rows w*16..+16
    {
        unsigned p = sd[w * 16 + nidx];
        const u16* sr = n1l0 + (p & 0xFFFFu) * 64;
        const u16* dr = n1l0 + (p >> 16) * 64;
        short8 as0 = *(const short8*)&sr[q * 8];
        short8 as1 = *(const short8*)&sr[32 + q * 8];
        short8 ad0 = *(const short8*)&dr[q * 8];
        short8 ad1 = *(const short8*)&dr[32 + q * 8];
#pragma unroll
        for (int jt = 0; jt < 8; jt++) {
            int j = jt * 16 + nidx;
            const u16* wr = Wfe0c + j * 128;
            short8 b0 = *(const short8*)&wr[q * 8];
            short8 b1 = *(const short8*)&wr[32 + q * 8];
            floatx4 acc = {0.f, 0.f, 0.f, 0.f};
            acc = __builtin_amdgcn_mfma_f32_16x16x32_bf16(as0, b0, acc, 0, 0, 0);
            acc = __builtin_amdgcn_mfma_f32_16x16x32_bf16(ad0, b0, acc, 0, 0, 0);
            acc = __builtin_amdgcn_mfma_f32_16x16x32_bf16(as1, b1, acc, 0, 0, 0);
            acc = __builtin_amdgcn_mfma_f32_16x16x32_bf16(ad1, b1, acc, 0, 0, 0);
            float bias = ldf(bfe0, j, m);
            float Pj = PN[j], Nj = PN[128 + j];
#pragma unroll
            for (int r = 0; r < 4; r++) {
                int e = w * 16 + q * 4 + r;   // D: row=(lane>>4)*4+reg, col=lane&15
                float a = aes[e];
                float v = acc[r] + bias + a * (a > 0.f ? Pj : Nj);
                h1s[e][j] = f2bf(fmaxf(v, 0.f));
            }
        }
    }
    __syncthreads();
    // GEMM2: e1' = relu(h1 @ We1^T) -> h2s (bf16)
    {
        const u16* ar = &h1s[w * 16 + nidx][0];
        short8 a0 = *(const short8*)&ar[q * 8];
        short8 a1 = *(const short8*)&ar[32 + q * 8];
        short8 a2 = *(const short8*)&ar[64 + q * 8];
        short8 a3 = *(const short8*)&ar[96 + q * 8];
#pragma unroll
        for (int ct = 0; ct < 4; ct++) {
            int c = ct * 16 + nidx;
            const u16* wr = We1c + c * 128;
            floatx4 acc = {0.f, 0.f, 0.f, 0.f};
            acc = __builtin_amdgcn_mfma_f32_16x16x32_bf16(a0, *(const short8*)&wr[q * 8], acc, 0, 0, 0);
            acc = __builtin_amdgcn_mfma_f32_16x16x32_bf16(a1, *(const short8*)&wr[32 + q * 8], acc, 0, 0, 0);
            acc = __builtin_amdgcn_mfma_f32_16x16x32_bf16(a2, *(const short8*)&wr[64 + q * 8], acc, 0, 0, 0);
            acc = __builtin_amdgcn_mfma_f32_16x16x32_bf16(a3, *(const short8*)&wr[96 + q * 8], acc, 0, 0, 0);
#pragma unroll
            for (int r = 0; r < 4; r++) {
                int e = w * 16 + q * 4 + r;
                h2s[e][c] = f2bf(fmaxf(acc[r], 0.f));
            }
        }
    }
    __syncthreads();
    // segmented reduction over sorted dst runs: 4 groups x 16 edges, 64 channels
    {
        int c = t & 63;
        int g = t >> 6;
        int ebeg = g * 16;
        float s = 0.f;
        int cur = sd[ebeg] >> 16;
        for (int e = ebeg; e < ebeg + 16; e++) {
            int d = sd[e] >> 16;
            if (d != cur) { atomicAdd(agg + cur * 64 + c, s); s = 0.f; cur = d; }
            s += bfu(h2s[e][c]);
        }
        atomicAdd(agg + cur * 64 + c, s);
    }
    // side product: sp/sn per-dst +/- ae sums
    if (t < 4) {
        int ebeg = t * 16;
        float p = 0.f, n = 0.f;
        int cur = sd[ebeg] >> 16;
        for (int e = ebeg; e < ebeg + 16; e++) {
            int d = sd[e] >> 16;
            if (d != cur) {
                if (p != 0.f) atomicAdd(sp + cur, p);
                if (n != 0.f) atomicAdd(sn + cur, n);
                p = 0.f; n = 0.f; cur = d;
            }
            float a = aes[e];
            p += fmaxf(a, 0.f); n += fminf(a, 0.f);
        }
        if (p != 0.f) atomicAdd(sp + cur, p);
        if (n != 0.f) atomicAdd(sn + cur, n);
    }
}

// K34: fused node MLP l0 + BN + node encoder l1 -> n1_l1 [50000 x 64] bf16. MFMA, 64 nodes/block.
__global__ __launch_bounds__(256) void k_node_l0(
    const u16* __restrict__ n1l0, const float* __restrict__ sp, const float* __restrict__ sn,
    const void* __restrict__ We0, const u16* __restrict__ Wfn0c, const void* __restrict__ bfn0,
    const void* __restrict__ g0, const void* __restrict__ b0,
    const void* __restrict__ rm0, const void* __restrict__ rv0,
    const u16* __restrict__ Wn1c, u16* __restrict__ n1l1, const int* __restrict__ mf) {
    int m = mf[0];
    __shared__ __align__(16) u16 fs[64][136];
    __shared__ __align__(16) u16 xs[64][136];
    int t = threadIdx.x;
    int n0 = blockIdx.x * 64;
    {
        int col = t & 127;
        int rbase = t >> 7;
        float wp = 0.f, wn = 0.f;
        if (col < 64) { float w0 = ldf(We0, col, m); wp = fmaxf(w0, 0.f); wn = fminf(w0, 0.f); }
#pragma unroll
        for (int i = 0; i < 32; i++) {
            int row = rbase + 2 * i;
            int n = n0 + row;
            float v = 0.f;
            if (n < NN) v = (col < 64) ? (wp * sp[n] + wn * sn[n]) : bfu(n1l0[n * 64 + col - 64]);
            fs[row][col] = f2bf(v);
        }
    }
    __syncthreads();
    int lane = t & 63, w = t >> 6, q = lane >> 4, nidx = lane & 15;
    {
        const u16* ar = &fs[w * 16 + nidx][0];
        short8 a0 = *(const short8*)&ar[q * 8];
        short8 a1 = *(const short8*)&ar[32 + q * 8];
        short8 a2 = *(const short8*)&ar[64 + q * 8];
        short8 a3 = *(const short8*)&ar[96 + q * 8];
#pragma unroll
        for (int jt = 0; jt < 8; jt++) {
            int j = jt * 16 + nidx;
            const u16* wr = Wfn0c + j * 128;
            floatx4 acc = {0.f, 0.f, 0.f, 0.f};
            acc = __builtin_amdgcn_mfma_f32_16x16x32_bf16(a0, *(const short8*)&wr[q * 8], acc, 0, 0, 0);
            acc = __builtin_amdgcn_mfma_f32_16x16x32_bf16(a1, *(const short8*)&wr[32 + q * 8], acc, 0, 0, 0);
            acc = __builtin_amdgcn_mfma_f32_16x16x32_bf16(a2, *(const short8*)&wr[64 + q * 8], acc, 0, 0, 0);
            acc = __builtin_amdgcn_mfma_f32_16x16x32_bf16(a3, *(const short8*)&wr[96 + q * 8], acc, 0, 0, 0);
            float bias = ldf(bfn0, j, m);
            float sc = ldf(g0, j, m) * rsqrtf(ldf(rv0, j, m) + BN_EPS);
            float sh = ldf(b0, j, m) - ldf(rm0, j, m) * sc;
#pragma unroll
            for (int r = 0; r < 4; r++) {
                int row = w * 16 + q * 4 + r;
                xs[row][j] = f2bf(fmaxf(acc[r] + bias, 0.f) * sc + sh);
            }
        }
    }
    __syncthreads();
    {
        const u16* ar = &xs[w * 16 + nidx][0];
        short8 a0 = *(const short8*)&ar[q * 8];
        short8 a1 = *(const short8*)&ar[32 + q * 8];
        short8 a2 = *(const short8*)&ar[64 + q * 8];
        short8 a3 = *(const short8*)&ar[96 + q * 8];
#pragma unroll
        for (int jt = 0; jt < 4; jt++) {
            int j = jt * 16 + nidx;
            const u16* wr = Wn1c + j * 128;
            floatx4 acc = {0.f, 0.f, 0.f, 0.f};
            acc = __builtin_amdgcn_mfma_f32_16x16x32_bf16(a0, *(const short8*)&wr[q * 8], acc, 0, 0, 0);
            acc = __builtin_amdgcn_mfma_f32_16x16x32_bf16(a1, *(const short8*)&wr[32 + q * 8], acc, 0, 0, 0);
            acc = __builtin_amdgcn_mfma_f32_16x16x32_bf16(a2, *(const short8*)&wr[64 + q * 8], acc, 0, 0, 0);
            acc = __builtin_amdgcn_mfma_f32_16x16x32_bf16(a3, *(const short8*)&wr[96 + q * 8], acc, 0, 0, 0);
#pragma unroll
            for (int r = 0; r < 4; r++) {
                int row = w * 16 + q * 4 + r;
                int n = n0 + row;
                if (n < NN) n1l1[n * 64 + j] = f2bf(fmaxf(acc[r], 0.f));
            }
        }
    }
}

// K6: node MLP l1 + BN -> d_out. MFMA, 64 nodes/block.
__global__ __launch_bounds__(256) void k_node_l1(
    const u16* __restrict__ n1l1, const float* __restrict__ agg,
    const u16* __restrict__ Wfn1c, const void* __restrict__ bfn1,
    const void* __restrict__ g1, const void* __restrict__ b1,
    const void* __restrict__ rm1, const void* __restrict__ rv1,
    void* __restrict__ out, const int* __restrict__ mf) {
    int m = mf[0];
    __shared__ __align__(16) u16 fs[64][136];
    int t = threadIdx.x;
    int n0 = blockIdx.x * 64;
    {
        int col = t & 127;
        int rbase = t >> 7;
#pragma unroll
        for (int i = 0; i < 32; i++) {
            int row = rbase + 2 * i;
            int n = n0 + row;
            float v = 0.f;
            if (n < NN) v = (col < 64) ? agg[n * 64 + col] : bfu(n1l1[n * 64 + col - 64]);
            fs[row][col] = f2bf(v);
        }
    }
    __syncthreads();
    int lane = t & 63, w = t >> 6, q = lane >> 4, nidx = lane & 15;
    const u16* ar = &fs[w * 16 + nidx][0];
    short8 a0 = *(const short8*)&ar[q * 8];
    short8 a1 = *(const short8*)&ar[32 + q * 8];
    short8 a2 = *(const short8*)&ar[64 + q * 8];
    short8 a3 = *(const short8*)&ar[96 + q * 8];
#pragma unroll
    for (int jt = 0; jt < 8; jt++) {
        int j = jt * 16 + nidx;
        const u16* wr = Wfn1c + j * 128;
        floatx4 acc = {0.f, 0.f, 0.f, 0.f};
        acc = __builtin_amdgcn_mfma_f32_16x16x32_bf16(a0, *(const short8*)&wr[q * 8], acc, 0, 0, 0);
        acc = __builtin_amdgcn_mfma_f32_16x16x32_bf16(a1, *(const short8*)&wr[32 + q * 8], acc, 0, 0, 0);
        acc = __builtin_amdgcn_mfma_f32_16x16x32_bf16(a2, *(const short8*)&wr[64 + q * 8], acc, 0, 0, 0);
        acc = __builtin_amdgcn_mfma_f32_16x16x32_bf16(a3, *(const short8*)&wr[96 + q * 8], acc, 0, 0, 0);
        float bias = ldf(bfn1, j, m);
        float sc = ldf(g1, j, m) * rsqrtf(ldf(rv1, j, m) + BN_EPS);
        float sh = ldf(b1, j, m) - ldf(rm1, j, m) * sc;
#pragma unroll
        for (int r = 0; r < 4; r++) {
            int row = w * 16 + q * 4 + r;
            int n = n0 + row;
            if (n < NN) {
                float v = fmaxf(acc[r] + bias, 0.f) * sc + sh;
                if (m) ((float*)out)[n * 128 + j] = v;
                else   ((u16*)out)[n * 128 + j] = f2bf(v);
            }
        }
    }
}

extern "C" void kernel_launch(void* const* d_in, const int* in_sizes, int n_in,
                              void* d_out, int out_size, void* d_ws, size_t ws_size,
                              hipStream_t stream) {
    const void* x    = d_in[0];
    const void* ea   = d_in[1];
    const int*  ei   = (const int*)d_in[2];
    const void* Wn0  = d_in[3];
    const void* We0  = d_in[4];
    const void* Wfn0 = d_in[5];
    const void* bfn0 = d_in[6];
    const void* Wfe0 = d_in[7];
    const void* bfe0 = d_in[8];
    const void* g0   = d_in[9];
    const void* b0   = d_in[10];
    const void* rm0  = d_in[11];
    const void* rv0  = d_in[12];
    const void* Wn1  = d_in[13];
    const void* We1  = d_in[14];
    const void* Wfn1 = d_in[15];
    const void* bfn1 = d_in[16];
    // d_in[17]/d_in[18] (l1_Wfe/l1_bfe): dead — layer-1 edge output discarded
    const void* g1   = d_in[19];
    const void* b1   = d_in[20];
    const void* rm1  = d_in[21];
    const void* rv1  = d_in[22];

    float* wsf = (float*)d_ws;
    float*    agg  = wsf;                         // 3.2M f32
    u16*      n1l0 = (u16*)(wsf + 3200000);       // 3.2M u16 (1.6M slots)
    unsigned* ssd  = (unsigned*)(wsf + 4800000);  // 1.6M uint — later aliased as n1l1
    u16*      n1l1 = (u16*)(wsf + 4800000);       // alias: written after ssd is dead
    u16*      sae  = (u16*)(wsf + 6400000);       // 1.6M u16 (0.8M slots)
    float*    sp   = wsf + 7200000;               // 50K
    float*    sn   = wsf + 7250000;               // 50K
    float*    PN   = wsf + 7300000;               // 256
    u16*      Wc   = (u16*)(wsf + 7300256);       // 65,536 u16 (32,768 slots)
    int*      off  = (int*)(wsf + 7333024);       // 50,000 int
    int*      bs   = (int*)(wsf + 7383024);       // 256 int
    int*      mode = (int*)(wsf + 7383280);
    u16* Wfe0c = Wc;
    u16* We1c  = Wc + 16384;
    u16* Wfn0c = Wc + 24576;
    u16* Wn1c  = Wc + 40960;
    u16* Wfn1c = Wc + 49152;

    hipMemsetAsync(sp, 0, 100000 * sizeof(float), stream);   // sp + sn
    hipMemsetAsync(agg, 0, 3200000 * sizeof(float), stream);
    hipMemsetAsync(off, 0, 50000 * sizeof(int), stream);

    k_detect<<<1, 256, 0, stream>>>((const u16*)x, mode);
    k_cvtw<<<256, 256, 0, stream>>>(Wfe0, We1, Wfn0, Wn1, Wfn1, Wc, mode);
    k_enc0<<<12500, 256, 0, stream>>>(x, Wn0, n1l0, mode);
    k_pn<<<1, 128, 0, stream>>>(We0, Wfe0, PN, mode);
    k_hist<<<6250, 256, 0, stream>>>(ei, off);
    k_scan1<<<196, 256, 0, stream>>>(off, bs);
    k_scan2<<<1, 256, 0, stream>>>(bs);
    k_scan3<<<196, 256, 0, stream>>>(off, bs);
    k_scatter<<<6250, 256, 0, stream>>>(ei, ea, off, ssd, sae, mode);
    k_edge<<<25000, 256, 0, stream>>>(ssd, sae, n1l0, Wfe0c, bfe0, PN, We1c,
                                      agg, sp, sn, mode);
    k_node_l0<<<782, 256, 0, stream>>>(n1l0, sp, sn, We0, Wfn0c, bfn0,
                                       g0, b0, rm0, rv0, Wn1c, n1l1, mode);
    k_node_l1<<<782, 256, 0, stream>>>(n1l1, agg, Wfn1c, bfn1,
                                       g1, b1, rm1, rv1, d_out, mode);
}

// Round 6
// 771.166 us; speedup vs baseline: 1.1665x; 1.0415x over previous
//
#include <hip/hip_runtime.h>

typedef unsigned short u16;
typedef __attribute__((ext_vector_type(8))) short short8;
typedef __attribute__((ext_vector_type(4))) float floatx4;

#define NN 50000
#define NE 1600000
#define BN_EPS 1e-5f

__device__ __forceinline__ float bfu(u16 u) {
    union { unsigned u32; float f; } v; v.u32 = ((unsigned)u) << 16; return v.f;
}
__device__ __forceinline__ u16 f2bf(float f) {
    union { float f; unsigned u; } v; v.f = f;
    unsigned r = v.u + 0x7FFFu + ((v.u >> 16) & 1u);
    return (u16)(r >> 16);
}
// mode m: 1 = buffers hold float32, 0 = buffers hold bf16
__device__ __forceinline__ float ldf(const void* p, int i, int m) {
    return m ? ((const float*)p)[i] : bfu(((const u16*)p)[i]);
}
#define MFMA __builtin_amdgcn_mfma_f32_16x16x32_bf16

// K_PREP: fused dtype-detect (per-block local) + weight canonicalize + PN + off zeroing.
// blocks 0..255: cvtw chunk; block 256: PN + publish mode.
// dst: Wfe0[16384] | We1[8192] | Wfn0[16384] | Wn1[8192] | Wfn1[16384]
__global__ __launch_bounds__(256) void k_prep(
    const u16* __restrict__ x16,
    const void* __restrict__ W0, const void* __restrict__ W1, const void* __restrict__ W2,
    const void* __restrict__ W3, const void* __restrict__ W4,
    const void* __restrict__ We0, const void* __restrict__ Wfe0,
    u16* __restrict__ dst, float* __restrict__ PN, int* __restrict__ off,
    int* __restrict__ mode) {
    __shared__ float smax[4];
    __shared__ int smode;
    int t = threadIdx.x;
    float mx = 0.f;
    for (int i = t; i < 4096; i += 256) mx = fmaxf(mx, fabsf(bfu(x16[i])));
#pragma unroll
    for (int o = 32; o > 0; o >>= 1) mx = fmaxf(mx, __shfl_down(mx, o));
    if ((t & 63) == 0) smax[t >> 6] = mx;
    __syncthreads();
    if (t == 0) {
        float m2 = fmaxf(fmaxf(smax[0], smax[1]), fmaxf(smax[2], smax[3]));
        smode = (m2 > 1e4f) ? 1 : 0;
    }
    __syncthreads();
    int m = smode;
    int bid = blockIdx.x;
    if (bid < 256) {
        int i = bid * 256 + t;
        const void* src; int o;
        if (i < 16384)      { src = W0; o = i; }
        else if (i < 24576) { src = W1; o = i - 16384; }
        else if (i < 40960) { src = W2; o = i - 24576; }
        else if (i < 49152) { src = W3; o = i - 40960; }
        else                { src = W4; o = i - 49152; }
        dst[i] = m ? f2bf(((const float*)src)[o]) : ((const u16*)src)[o];
    } else {
        if (t < 128) {
            int j = t;
            float p = 0.f, n = 0.f;
            for (int k = 0; k < 64; k++) {
                float w = ldf(We0, k, m);
                float wf = ldf(Wfe0, j * 128 + 64 + k, m);
                p += fmaxf(w, 0.f) * wf;
                n += fminf(w, 0.f) * wf;
            }
            PN[j] = p; PN[128 + j] = n;
        }
        if (t == 128) mode[0] = m;
    }
    int i2 = bid * 256 + t;
    if (i2 < NN) off[i2] = 0;
}

// K1: n1_l0[n][c] = relu(sum_i x[n][i]*Wn0[c][i])  [50000 x 64] bf16. 16 nodes/block.
__global__ __launch_bounds__(256) void k_enc0(const void* __restrict__ x, const void* __restrict__ Wn,
                                              u16* __restrict__ n1, const int* __restrict__ mf) {
    int m = mf[0];
    __shared__ float Wns[64 * 17];
    __shared__ float xsh[16][17];
    int t = threadIdx.x;
    int n0 = blockIdx.x * 16;
    for (int i = t; i < 1024; i += 256) Wns[(i >> 4) * 17 + (i & 15)] = ldf(Wn, i, m);
    { int nn = t >> 4, i = t & 15; xsh[nn][i] = ldf(x, (n0 + nn) * 16 + i, m); }
    __syncthreads();
    int c = t & 63;
#pragma unroll
    for (int nb = 0; nb < 4; nb++) {
        int nn = nb * 4 + (t >> 6);
        float acc = 0.f;
#pragma unroll
        for (int i = 0; i < 16; i++) acc += xsh[nn][i] * Wns[c * 17 + i];
        n1[(n0 + nn) * 64 + c] = f2bf(fmaxf(acc, 0.f));
    }
}

// SORT pass 1: histogram of dst
__global__ __launch_bounds__(256) void k_hist(const int* __restrict__ ei, int* __restrict__ off) {
    int e = blockIdx.x * 256 + threadIdx.x;
    atomicAdd(off + ei[NE + e], 1);
}

// two-level scan
__global__ __launch_bounds__(256) void k_scan1(const int* __restrict__ off, int* __restrict__ bs) {
    __shared__ int sh[4];
    int t = threadIdx.x;
    int i = blockIdx.x * 256 + t;
    int v = (i < NN) ? off[i] : 0;
#pragma unroll
    for (int o = 32; o > 0; o >>= 1) v += __shfl_down(v, o);
    if ((t & 63) == 0) sh[t >> 6] = v;
    __syncthreads();
    if (t == 0) bs[blockIdx.x] = sh[0] + sh[1] + sh[2] + sh[3];
}
__global__ __launch_bounds__(256) void k_scan2(int* __restrict__ bs) {
    __shared__ int s[256];
    int t = threadIdx.x;
    int v = (t < 196) ? bs[t] : 0;
    s[t] = v;
    __syncthreads();
    for (int o = 1; o < 256; o <<= 1) {
        int u = (t >= o) ? s[t - o] : 0;
        __syncthreads();
        s[t] += u;
        __syncthreads();
    }
    if (t < 196) bs[t] = s[t] - v;
}
__global__ __launch_bounds__(256) void k_scan3(int* __restrict__ off, const int* __restrict__ bs) {
    __shared__ int s[256];
    int t = threadIdx.x;
    int i = blockIdx.x * 256 + t;
    int v = (i < NN) ? off[i] : 0;
    s[t] = v;
    __syncthreads();
    for (int o = 1; o < 256; o <<= 1) {
        int u = (t >= o) ? s[t - o] : 0;
        __syncthreads();
        s[t] += u;
        __syncthreads();
    }
    if (i < NN) off[i] = bs[blockIdx.x] + s[t] - v;
}

// SORT pass 3: scatter into dst-sorted order. sd = src | dst<<16, ae bf16.
__global__ __launch_bounds__(256) void k_scatter(const int* __restrict__ ei, const void* __restrict__ ea,
                                                 int* __restrict__ off,
                                                 unsigned* __restrict__ ssd, u16* __restrict__ sae,
                                                 const int* __restrict__ mf) {
    int m = mf[0];
    int e = blockIdx.x * 256 + threadIdx.x;
    int srcv = ei[e], d = ei[NE + e];
    int p = atomicAdd(off + d, 1);
    ssd[p] = (unsigned)srcv | ((unsigned)d << 16);
    sae[p] = f2bf(ldf(ea, e, m));
}

// K5: fused edge pipeline, dst-sorted, fully per-wave (no inter-wave barriers).
// Wave w owns 32 edges (2 subtiles of 16) and private LDS regions.
__global__ __launch_bounds__(256) void k_edge(
    const unsigned* __restrict__ ssd, const u16* __restrict__ sae,
    const u16* __restrict__ n1l0,
    const u16* __restrict__ Wfe0c, const void* __restrict__ bfe0,
    const float* __restrict__ PN,
    const u16* __restrict__ We1c,
    float* __restrict__ agg, float* __restrict__ sp, float* __restrict__ sn,
    const int* __restrict__ mf) {
    int m = mf[0];
    __shared__ __align__(16) u16 h1s[4][16][136];   // per-wave regions
    __shared__ __align__(16) u16 h2s[4][16][72];
    int t = threadIdx.x;
    int lane = t & 63, w = t >> 6, q = lane >> 4, nidx = lane & 15;
    int ew = blockIdx.x * 128 + w * 32;
    u16 (*h1w)[136] = h1s[w];
    u16 (*h2w)[72] = h2s[w];

    // upfront: edge meta + all 8 A-fragment gathers in flight
    unsigned p0 = ssd[ew + nidx];
    unsigned p1 = ssd[ew + 16 + nidx];
    float ae0 = bfu(sae[ew + nidx]);
    float ae1 = bfu(sae[ew + 16 + nidx]);
    const u16* sr0 = n1l0 + (p0 & 0xFFFFu) * 64;
    const u16* dr0 = n1l0 + (p0 >> 16) * 64;
    const u16* sr1 = n1l0 + (p1 & 0xFFFFu) * 64;
    const u16* dr1 = n1l0 + (p1 >> 16) * 64;
    short8 as0[2], as1[2], ad0[2], ad1[2];
    as0[0] = *(const short8*)&sr0[q * 8];      as1[0] = *(const short8*)&sr0[32 + q * 8];
    ad0[0] = *(const short8*)&dr0[q * 8];      ad1[0] = *(const short8*)&dr0[32 + q * 8];
    as0[1] = *(const short8*)&sr1[q * 8];      as1[1] = *(const short8*)&sr1[32 + q * 8];
    ad0[1] = *(const short8*)&dr1[q * 8];      ad1[1] = *(const short8*)&dr1[32 + q * 8];

#pragma unroll
    for (int sub = 0; sub < 2; sub++) {
        unsigned pm = sub ? p1 : p0;
        float am = sub ? ae1 : ae0;
        float a4[4];
#pragma unroll
        for (int r = 0; r < 4; r++) a4[r] = __shfl(am, q * 4 + r);
        // GEMM1: h1 = relu((n1[src]+n1[dst]) @ Wfe0[:,:64]^T + ae*PN + bfe0)
#pragma unroll
        for (int jt = 0; jt < 8; jt++) {
            int j = jt * 16 + nidx;
            const u16* wr = Wfe0c + j * 128;
            short8 b0 = *(const short8*)&wr[q * 8];
            short8 b1 = *(const short8*)&wr[32 + q * 8];
            floatx4 acc = {0.f, 0.f, 0.f, 0.f};
            acc = MFMA(as0[sub], b0, acc, 0, 0, 0);
            acc = MFMA(ad0[sub], b0, acc, 0, 0, 0);
            acc = MFMA(as1[sub], b1, acc, 0, 0, 0);
            acc = MFMA(ad1[sub], b1, acc, 0, 0, 0);
            float bias = ldf(bfe0, j, m);
            float Pj = PN[j], Nj = PN[128 + j];
#pragma unroll
            for (int r = 0; r < 4; r++) {
                float a = a4[r];
                float v = acc[r] + bias + a * (a > 0.f ? Pj : Nj);
                h1w[q * 4 + r][j] = f2bf(fmaxf(v, 0.f));   // C: row=q*4+r, col=nidx(+16jt)
            }
        }
        asm volatile("s_waitcnt lgkmcnt(0)" ::: "memory");   // own-wave h1 writes visible
        // GEMM2: e1' = relu(h1 @ We1^T)
        {
            const u16* ar = &h1w[nidx][0];
            short8 a0 = *(const short8*)&ar[q * 8];
            short8 a1 = *(const short8*)&ar[32 + q * 8];
            short8 a2 = *(const short8*)&ar[64 + q * 8];
            short8 a3 = *(const short8*)&ar[96 + q * 8];
#pragma unroll
            for (int ct = 0; ct < 4; ct++) {
                int c = ct * 16 + nidx;
                const u16* wr = We1c + c * 128;
                floatx4 acc = {0.f, 0.f, 0.f, 0.f};
                acc = MFMA(a0, *(const short8*)&wr[q * 8], acc, 0, 0, 0);
                acc = MFMA(a1, *(const short8*)&wr[32 + q * 8], acc, 0, 0, 0);
                acc = MFMA(a2, *(const short8*)&wr[64 + q * 8], acc, 0, 0, 0);
                acc = MFMA(a3, *(const short8*)&wr[96 + q * 8], acc, 0, 0, 0);
#pragma unroll
                for (int r = 0; r < 4; r++) h2w[q * 4 + r][c] = f2bf(fmaxf(acc[r], 0.f));
            }
        }
        asm volatile("s_waitcnt lgkmcnt(0)" ::: "memory");
        // segmented reduce over sorted dst runs; lane = channel; dst via shuffles
        {
            float s = 0.f, ps = 0.f, ns = 0.f;
            int cur = (int)(__shfl(pm, 0) >> 16);
            for (int e = 0; e < 16; e++) {
                int d = (int)(__shfl(pm, e) >> 16);   // wave-uniform
                float a = __shfl(am, e);
                if (d != cur) {
                    atomicAdd(agg + cur * 64 + lane, s);
                    if (lane == 0) {
                        if (ps != 0.f) atomicAdd(sp + cur, ps);
                        if (ns != 0.f) atomicAdd(sn + cur, ns);
                    }
                    s = 0.f; ps = 0.f; ns = 0.f; cur = d;
                }
                s += bfu(h2w[e][lane]);
                ps += fmaxf(a, 0.f); ns += fminf(a, 0.f);
            }
            atomicAdd(agg + cur * 64 + lane, s);
            if (lane == 0) {
                if (ps != 0.f) atomicAdd(sp + cur, ps);
                if (ns != 0.f) atomicAdd(sn + cur, ns);
            }
        }
    }
}

// K_NODE: merged node MLP l0 + BN + encoder l1 + node MLP l1 + BN -> d_out. 64 nodes/block.
__global__ __launch_bounds__(256) void k_node(
    const u16* __restrict__ n1l0, const float* __restrict__ sp, const float* __restrict__ sn,
    const float* __restrict__ agg,
    const void* __restrict__ We0, const u16* __restrict__ Wfn0c, const void* __restrict__ bfn0,
    const void* __restrict__ g0, const void* __restrict__ b0,
    const void* __restrict__ rm0, const void* __restrict__ rv0,
    const u16* __restrict__ Wn1c,
    const u16* __restrict__ Wfn1c, const void* __restrict__ bfn1,
    const void* __restrict__ g1, const void* __restrict__ b1,
    const void* __restrict__ rm1, const void* __restrict__ rv1,
    void* __restrict__ out, const int* __restrict__ mf) {
    int m = mf[0];
    __shared__ __align__(16) u16 fs[64][136];
    __shared__ __align__(16) u16 xs[64][136];
    int t = threadIdx.x;
    int n0 = blockIdx.x * 64;
    {   // fs = concat(analytic agg_l0, n1_l0)
        int col = t & 127, rbase = t >> 7;
        float wp = 0.f, wn = 0.f;
        if (col < 64) { float w0 = ldf(We0, col, m); wp = fmaxf(w0, 0.f); wn = fminf(w0, 0.f); }
#pragma unroll
        for (int i = 0; i < 32; i++) {
            int row = rbase + 2 * i;
            int n = n0 + row;
            float v = 0.f;
            if (n < NN) v = (col < 64) ? (wp * sp[n] + wn * sn[n]) : bfu(n1l0[n * 64 + col - 64]);
            fs[row][col] = f2bf(v);
        }
    }
    __syncthreads();
    int lane = t & 63, w = t >> 6, q = lane >> 4, nidx = lane & 15;
    {   // GEMM1: x1 = BN(relu(fs @ Wfn0^T + bfn0)) -> xs (own rows)
        const u16* ar = &fs[w * 16 + nidx][0];
        short8 a0 = *(const short8*)&ar[q * 8];
        short8 a1 = *(const short8*)&ar[32 + q * 8];
        short8 a2 = *(const short8*)&ar[64 + q * 8];
        short8 a3 = *(const short8*)&ar[96 + q * 8];
#pragma unroll
        for (int jt = 0; jt < 8; jt++) {
            int j = jt * 16 + nidx;
            const u16* wr = Wfn0c + j * 128;
            floatx4 acc = {0.f, 0.f, 0.f, 0.f};
            acc = MFMA(a0, *(const short8*)&wr[q * 8], acc, 0, 0, 0);
            acc = MFMA(a1, *(const short8*)&wr[32 + q * 8], acc, 0, 0, 0);
            acc = MFMA(a2, *(const short8*)&wr[64 + q * 8], acc, 0, 0, 0);
            acc = MFMA(a3, *(const short8*)&wr[96 + q * 8], acc, 0, 0, 0);
            float bias = ldf(bfn0, j, m);
            float sc = ldf(g0, j, m) * rsqrtf(ldf(rv0, j, m) + BN_EPS);
            float sh = ldf(b0, j, m) - ldf(rm0, j, m) * sc;
#pragma unroll
            for (int r = 0; r < 4; r++)
                xs[w * 16 + q * 4 + r][j] = f2bf(fmaxf(acc[r] + bias, 0.f) * sc + sh);
        }
    }
    asm volatile("s_waitcnt lgkmcnt(0)" ::: "memory");   // own-wave xs writes
    {   // GEMM2: n1_l1 = relu(xs @ Wn1^T) -> fs[row][64+j] (own rows)
        const u16* ar = &xs[w * 16 + nidx][0];
        short8 a0 = *(const short8*)&ar[q * 8];
        short8 a1 = *(const short8*)&ar[32 + q * 8];
        short8 a2 = *(const short8*)&ar[64 + q * 8];
        short8 a3 = *(const short8*)&ar[96 + q * 8];
#pragma unroll
        for (int jt = 0; jt < 4; jt++) {
            int j = jt * 16 + nidx;
            const u16* wr = Wn1c + j * 128;
            floatx4 acc = {0.f, 0.f, 0.f, 0.f};
            acc = MFMA(a0, *(const short8*)&wr[q * 8], acc, 0, 0, 0);
            acc = MFMA(a1, *(const short8*)&wr[32 + q * 8], acc, 0, 0, 0);
            acc = MFMA(a2, *(const short8*)&wr[64 + q * 8], acc, 0, 0, 0);
            acc = MFMA(a3, *(const short8*)&wr[96 + q * 8], acc, 0, 0, 0);
#pragma unroll
            for (int r = 0; r < 4; r++)
                fs[w * 16 + q * 4 + r][64 + j] = f2bf(fmaxf(acc[r], 0.f));
        }
    }
    __syncthreads();
    {   // stage agg into fs[][0..63]
#pragma unroll
        for (int i = 0; i < 16; i++) {
            int idx = i * 256 + t;
            int row = idx >> 6, c = idx & 63;
            int n = n0 + row;
            fs[row][c] = f2bf((n < NN) ? agg[n * 64 + c] : 0.f);
        }
    }
    __syncthreads();
    {   // GEMM3: out = BN(relu(fs @ Wfn1^T + bfn1))
        const u16* ar = &fs[w * 16 + nidx][0];
        short8 a0 = *(const short8*)&ar[q * 8];
        short8 a1 = *(const short8*)&ar[32 + q * 8];
        short8 a2 = *(const short8*)&ar[64 + q * 8];
        short8 a3 = *(const short8*)&ar[96 + q * 8];
#pragma unroll
        for (int jt = 0; jt < 8; jt++) {
            int j = jt * 16 + nidx;
            const u16* wr = Wfn1c + j * 128;
            floatx4 acc = {0.f, 0.f, 0.f, 0.f};
            acc = MFMA(a0, *(const short8*)&wr[q * 8], acc, 0, 0, 0);
            acc = MFMA(a1, *(const short8*)&wr[32 + q * 8], acc, 0, 0, 0);
            acc = MFMA(a2, *(const short8*)&wr[64 + q * 8], acc, 0, 0, 0);
            acc = MFMA(a3, *(const short8*)&wr[96 + q * 8], acc, 0, 0, 0);
            float bias = ldf(bfn1, j, m);
            float sc = ldf(g1, j, m) * rsqrtf(ldf(rv1, j, m) + BN_EPS);
            float sh = ldf(b1, j, m) - ldf(rm1, j, m) * sc;
#pragma unroll
            for (int r = 0; r < 4; r++) {
                int n = n0 + w * 16 + q * 4 + r;
                if (n < NN) {
                    float v = fmaxf(acc[r] + bias, 0.f) * sc + sh;
                    if (m) ((float*)out)[n * 128 + j] = v;
                    else   ((u16*)out)[n * 128 + j] = f2bf(v);
                }
            }
        }
    }
}

extern "C" void kernel_launch(void* const* d_in, const int* in_sizes, int n_in,
                              void* d_out, int out_size, void* d_ws, size_t ws_size,
                              hipStream_t stream) {
    const void* x    = d_in[0];
    const void* ea   = d_in[1];
    const int*  ei   = (const int*)d_in[2];
    const void* Wn0  = d_in[3];
    const void* We0  = d_in[4];
    const void* Wfn0 = d_in[5];
    const void* bfn0 = d_in[6];
    const void* Wfe0 = d_in[7];
    const void* bfe0 = d_in[8];
    const void* g0   = d_in[9];
    const void* b0   = d_in[10];
    const void* rm0  = d_in[11];
    const void* rv0  = d_in[12];
    const void* Wn1  = d_in[13];
    const void* We1  = d_in[14];
    const void* Wfn1 = d_in[15];
    const void* bfn1 = d_in[16];
    // d_in[17]/d_in[18] (l1_Wfe/l1_bfe): dead — layer-1 edge output discarded
    const void* g1   = d_in[19];
    const void* b1   = d_in[20];
    const void* rm1  = d_in[21];
    const void* rv1  = d_in[22];

    float* wsf = (float*)d_ws;
    float*    agg  = wsf;                         // 3.2M f32
    float*    sp   = wsf + 3200000;               // 50K
    float*    sn   = wsf + 3250000;               // 50K
    u16*      n1l0 = (u16*)(wsf + 3300000);       // 3.2M u16 (1.6M slots)
    unsigned* ssd  = (unsigned*)(wsf + 4900000);  // 1.6M uint
    u16*      sae  = (u16*)(wsf + 6500000);       // 1.6M u16 (0.8M slots)
    float*    PN   = wsf + 7300000;               // 256
    u16*      Wc   = (u16*)(wsf + 7300256);       // 65,536 u16 (32,768 slots)
    int*      off  = (int*)(wsf + 7333024);       // 50,000 int
    int*      bs   = (int*)(wsf + 7383024);       // 256 int
    int*      mode = (int*)(wsf + 7383280);
    u16* Wfe0c = Wc;
    u16* We1c  = Wc + 16384;
    u16* Wfn0c = Wc + 24576;
    u16* Wn1c  = Wc + 40960;
    u16* Wfn1c = Wc + 49152;

    hipMemsetAsync(agg, 0, 3300000 * sizeof(float), stream);   // agg + sp + sn

    k_prep<<<257, 256, 0, stream>>>((const u16*)x, Wfe0, We1, Wfn0, Wn1, Wfn1,
                                    We0, Wfe0, Wc, PN, off, mode);
    k_enc0<<<3125, 256, 0, stream>>>(x, Wn0, n1l0, mode);
    k_hist<<<6250, 256, 0, stream>>>(ei, off);
    k_scan1<<<196, 256, 0, stream>>>(off, bs);
    k_scan2<<<1, 256, 0, stream>>>(bs);
    k_scan3<<<196, 256, 0, stream>>>(off, bs);
    k_scatter<<<6250, 256, 0, stream>>>(ei, ea, off, ssd, sae, mode);
    k_edge<<<12500, 256, 0, stream>>>(ssd, sae, n1l0, Wfe0c, bfe0, PN, We1c,
                                      agg, sp, sn, mode);
    k_node<<<782, 256, 0, stream>>>(n1l0, sp, sn, agg, We0, Wfn0c, bfn0,
                                    g0, b0, rm0, rv0, Wn1c, Wfn1c, bfn1,
                                    g1, b1, rm1, rv1, d_out, mode);
}